// Round 7
// baseline (140.159 us; speedup 1.0000x reference)
//
#include <hip/hip_runtime.h>
#include <hip/hip_bf16.h>

#define DD 6
#define FF 64
#define NS 30     // 2*D*RANK + D
#define TS16 32   // bf16 elements per table row (64 B)
#define UPB 32    // units per block in precompute

typedef float fx4 __attribute__((ext_vector_type(4)));

__device__ __forceinline__ float fast_sigmoid(float v) {
    return __builtin_amdgcn_rcpf(1.0f + __expf(-v));
}
__device__ __forceinline__ void nt_store4(float* p, float a, float b, float c, float d) {
    fx4 v = {a, b, c, d};
    __builtin_nontemporal_store(v, (fx4*)p);
}

// Precompute: blocks [0,nbN) nodes, [nbN,nbN+nbE) edges. (unchanged from R5: ~30us, near read floor)
__global__ __launch_bounds__(256) void precompute_kernel(
    const float* __restrict__ x, const float* __restrict__ e,
    const float* __restrict__ W, const float* __restrict__ bias,
    __hip_bfloat16* __restrict__ xW, __hip_bfloat16* __restrict__ eW,
    int N, int E, int nbN)
{
    __shared__ float means[UPB][68];
    bool isNode = (int)blockIdx.x < nbN;
    int ucount  = isNode ? N : E;
    int ubase   = (isNode ? blockIdx.x : (blockIdx.x - nbN)) * UPB;
    const float* src = isNode ? x : e;
    const float* Wp  = W + (isNode ? 0 : FF * NS);
    __hip_bfloat16* dst = isNode ? xW : eW;

    int tid = threadIdx.x, wid = tid >> 6, lane = tid & 63;

    #pragma unroll
    for (int i = 0; i < 8; ++i) {
        int s = wid * 8 + i;
        int u = ubase + s;
        float m = 0.f;
        if (u < ucount) {
            const float* p = src + (size_t)u * (DD * FF) + lane;
            #pragma unroll
            for (int d = 0; d < DD; ++d) m += __builtin_nontemporal_load(p + d * FF);
        }
        means[s][lane] = m * (1.0f / 6.0f);
    }
    __syncthreads();

    int j30 = lane & 31;
    bool jval = j30 < NS;
    int j = jval ? j30 : 0;
    float wreg[FF];
    #pragma unroll
    for (int f = 0; f < FF; ++f) wreg[f] = Wp[f * NS + j];   // 15 KB, L1-resident
    float bj = isNode ? bias[j] : 0.f;

    #pragma unroll
    for (int t = 0; t < 4; ++t) {
        int sl = wid * 8 + 2 * t + (lane >> 5);
        int u  = ubase + sl;
        const fx4* mp4 = (const fx4*)(&means[sl][0]);
        float o = bj;
        #pragma unroll
        for (int q = 0; q < 16; ++q) {
            fx4 m4 = mp4[q];
            o = fmaf(m4.x, wreg[4 * q + 0], o);
            o = fmaf(m4.y, wreg[4 * q + 1], o);
            o = fmaf(m4.z, wreg[4 * q + 2], o);
            o = fmaf(m4.w, wreg[4 * q + 3], o);
        }
        if (jval && u < ucount)
            dst[(size_t)u * TS16 + j30] = __float2bfloat16(o);
    }
}

// Fused, wave-autonomous (no __syncthreads): each wave owns a 32x36 LDS slice.
// Correctness mechanics (fix for R6): (1) r/c come from per-wave LDS staging
// written by each thread to its OWN slot before any read — no __shfl from
// possibly-exited lanes; (2) compiler memory fences separate the LDS write
// phase from the read phase; the per-wave in-order DS pipe provides the HW
// ordering. All output streams written with nt float4 stores.
__global__ __launch_bounds__(256) void fused_kernel(
    const int* __restrict__ rows, const int* __restrict__ cols,
    const __hip_bfloat16* __restrict__ xW, const __hip_bfloat16* __restrict__ eW,
    float* __restrict__ out_idx0, float* __restrict__ out_idx1,
    float* __restrict__ out_attr, int nnz)
{
    __shared__ float mlds[4][32 * 36];   // 18432 B
    __shared__ int rlds[256], clds[256];
    int tid  = threadIdx.x, wid = tid >> 6, lane = tid & 63;
    int bb   = blockIdx.x * 256;
    int k    = bb + tid;
    bool act = k < nnz;

    float mp[36];
    if (act) {
        int r = rows[k];
        int c = cols[k];
        rlds[tid] = r;                      // own slot; read only within this wave
        clds[tid] = c;
        const uint4* xp = (const uint4*)(xW + (size_t)r * TS16);
        const uint4* ep = (const uint4*)(eW + (size_t)c * TS16);
        uint4 xa0 = xp[0], xa1 = xp[1], xa2 = xp[2], xa3 = xp[3];
        uint4 ea0 = ep[0], ea1 = ep[1], ea2 = ep[2], ea3 = ep[3];
        uint wx[16] = {xa0.x, xa0.y, xa0.z, xa0.w, xa1.x, xa1.y, xa1.z, xa1.w,
                       xa2.x, xa2.y, xa2.z, xa2.w, xa3.x, xa3.y, xa3.z, xa3.w};
        uint we[16] = {ea0.x, ea0.y, ea0.z, ea0.w, ea1.x, ea1.y, ea1.z, ea1.w,
                       ea2.x, ea2.y, ea2.z, ea2.w, ea3.x, ea3.y, ea3.z, ea3.w};
        float s[NS];
        #pragma unroll
        for (int j2 = 0; j2 < NS; ++j2) {
            uint ux = (j2 & 1) ? (wx[j2 >> 1] & 0xffff0000u) : (wx[j2 >> 1] << 16);
            uint ue = (j2 & 1) ? (we[j2 >> 1] & 0xffff0000u) : (we[j2 >> 1] << 16);
            s[j2] = fast_sigmoid(__uint_as_float(ux) + __uint_as_float(ue));
        }
        #pragma unroll
        for (int i = 0; i < DD; ++i) {
            float a0 = s[i * 2], a1 = s[i * 2 + 1];
            #pragma unroll
            for (int jj = 0; jj < DD; ++jj) {
                float v = fmaf(a0, s[12 + jj * 2], a1 * s[13 + jj * 2]);
                if (i == jj) v += s[24 + i];
                mp[i * 6 + jj] = v;
            }
        }
    }

    float* wl = mlds[wid];
    int wbase = bb + wid * 64;
    #pragma unroll
    for (int h = 0; h < 2; ++h) {
        if (act && (lane >> 5) == h) {
            float* ml = wl + (lane & 31) * 36;
            #pragma unroll
            for (int q = 0; q < 9; ++q) {
                fx4 v = {mp[4 * q], mp[4 * q + 1], mp[4 * q + 2], mp[4 * q + 3]};
                *(fx4*)(ml + 4 * q) = v;            // ds_write_b128
            }
        }
        asm volatile("" ::: "memory");              // no compiler reorder across phases
        int b2  = wbase + h * 32;
        int cnt = nnz - b2; if (cnt > 32) cnt = 32;
        if (cnt > 0) {
            int tot = cnt * 36;                     // 4-divisible
            size_t ob = (size_t)b2 * 36;
            float* ga = out_attr + ob;
            float* g0 = out_idx0 + ob;
            float* g1 = out_idx1 + ob;
            int lb = wid * 64 + h * 32;             // block-local nnz base (this wave's half)
            for (int g = lane * 4; g < tot; g += 256) {
                int l = g / 36;
                int m = g - l * 36;                 // 4-aligned; same l for all 4
                fx4 a = *(const fx4*)(wl + l * 36 + m);   // ds_read_b128
                int rr = rlds[lb + l];
                int cc = clds[lb + l];
                float v0[4], v1[4];
                #pragma unroll
                for (int i = 0; i < 4; ++i) {
                    int mm = m + i;
                    int m6 = mm / 6;
                    v0[i] = (float)(6 * rr + m6);
                    v1[i] = (float)(6 * cc + (mm - m6 * 6));
                }
                nt_store4(ga + g, a.x, a.y, a.z, a.w);
                nt_store4(g0 + g, v0[0], v0[1], v0[2], v0[3]);
                nt_store4(g1 + g, v1[0], v1[1], v1[2], v1[3]);
            }
        }
        asm volatile("" ::: "memory");              // reads done before next half overwrites
    }
}

// Fallback split kernels (only if ws_size can't hold the 7.7 MB tables; tables
// then live in the idx0 output region, so idx writes must come last). Barriers
// retained here — correctness over speed on the fallback path.
__global__ __launch_bounds__(256) void sheaf_kernel(
    const int* __restrict__ rows, const int* __restrict__ cols,
    const __hip_bfloat16* __restrict__ xW, const __hip_bfloat16* __restrict__ eW,
    float* __restrict__ out_attr, int nnz)
{
    __shared__ float mlds[4][32 * 36];
    int tid = threadIdx.x, wid = tid >> 6, lane = tid & 63;
    int bb  = blockIdx.x * 256;
    int k   = bb + tid;
    bool act = k < nnz;
    float mp[36];
    if (act) {
        int r = rows[k];
        int c = cols[k];
        const uint4* xp = (const uint4*)(xW + (size_t)r * TS16);
        const uint4* ep = (const uint4*)(eW + (size_t)c * TS16);
        uint4 xa0 = xp[0], xa1 = xp[1], xa2 = xp[2], xa3 = xp[3];
        uint4 ea0 = ep[0], ea1 = ep[1], ea2 = ep[2], ea3 = ep[3];
        uint wx[16] = {xa0.x, xa0.y, xa0.z, xa0.w, xa1.x, xa1.y, xa1.z, xa1.w,
                       xa2.x, xa2.y, xa2.z, xa2.w, xa3.x, xa3.y, xa3.z, xa3.w};
        uint we[16] = {ea0.x, ea0.y, ea0.z, ea0.w, ea1.x, ea1.y, ea1.z, ea1.w,
                       ea2.x, ea2.y, ea2.z, ea2.w, ea3.x, ea3.y, ea3.z, ea3.w};
        float s[NS];
        #pragma unroll
        for (int j2 = 0; j2 < NS; ++j2) {
            uint ux = (j2 & 1) ? (wx[j2 >> 1] & 0xffff0000u) : (wx[j2 >> 1] << 16);
            uint ue = (j2 & 1) ? (we[j2 >> 1] & 0xffff0000u) : (we[j2 >> 1] << 16);
            s[j2] = fast_sigmoid(__uint_as_float(ux) + __uint_as_float(ue));
        }
        #pragma unroll
        for (int i = 0; i < DD; ++i) {
            float a0 = s[i * 2], a1 = s[i * 2 + 1];
            #pragma unroll
            for (int jj = 0; jj < DD; ++jj) {
                float v = fmaf(a0, s[12 + jj * 2], a1 * s[13 + jj * 2]);
                if (i == jj) v += s[24 + i];
                mp[i * 6 + jj] = v;
            }
        }
    }
    float* wl = mlds[wid];
    int wbase = bb + wid * 64;
    #pragma unroll
    for (int h = 0; h < 2; ++h) {
        if (h) __syncthreads();
        if (act && (lane >> 5) == h) {
            float* ml = wl + (lane & 31) * 36;
            #pragma unroll
            for (int q = 0; q < 9; ++q) {
                fx4 v = {mp[4 * q], mp[4 * q + 1], mp[4 * q + 2], mp[4 * q + 3]};
                *(fx4*)(ml + 4 * q) = v;
            }
        }
        __syncthreads();
        int b2  = wbase + h * 32;
        int cnt = nnz - b2; if (cnt > 32) cnt = 32;
        if (cnt > 0) {
            int tot = cnt * 36;
            float* gp = out_attr + (size_t)b2 * 36;
            for (int g = lane * 4; g < tot; g += 256) {
                int l = g / 36;
                int m = g - l * 36;
                fx4 a = *(const fx4*)(wl + l * 36 + m);
                nt_store4(gp + g, a.x, a.y, a.z, a.w);
            }
        }
    }
}

__global__ __launch_bounds__(256) void idx_kernel(
    const int* __restrict__ rows, const int* __restrict__ cols,
    float* __restrict__ out_idx0, float* __restrict__ out_idx1, int tot)
{
    int g = (blockIdx.x * 256 + threadIdx.x) * 4;
    if (g >= tot) return;
    float v0[4], v1[4];
    #pragma unroll
    for (int i = 0; i < 4; ++i) {
        int gg = g + i;
        int l  = gg / 36;
        int m  = gg - l * 36;
        int m6 = m / 6;
        v0[i] = (float)(6 * rows[l] + m6);
        v1[i] = (float)(6 * cols[l] + (m - m6 * 6));
    }
    nt_store4(out_idx0 + g, v0[0], v0[1], v0[2], v0[3]);
    nt_store4(out_idx1 + g, v1[0], v1[1], v1[2], v1[3]);
}

extern "C" void kernel_launch(void* const* d_in, const int* in_sizes, int n_in,
                              void* d_out, int out_size, void* d_ws, size_t ws_size,
                              hipStream_t stream)
{
    const float* x = (const float*)d_in[0];
    const float* e = (const float*)d_in[1];
    const float* W = (const float*)d_in[2];
    const float* b = (const float*)d_in[3];
    const int* hidx = (const int*)d_in[4];

    int N   = in_sizes[0] / (DD * FF);
    int E   = in_sizes[1] / (DD * FF);
    int nnz = in_sizes[4] / 2;
    const int* rows = hidx;
    const int* cols = hidx + nnz;

    float* out = (float*)d_out;
    size_t M = (size_t)nnz * 36;
    float* out_idx0 = out;
    float* out_idx1 = out + M;
    float* out_attr = out + 2 * M;

    size_t tableBytes = ((size_t)N + (size_t)E) * TS16 * sizeof(__hip_bfloat16);
    bool haveWs = (ws_size >= tableBytes);
    __hip_bfloat16* xW = haveWs ? (__hip_bfloat16*)d_ws
                                : (__hip_bfloat16*)out_idx0;   // fallback staging
    __hip_bfloat16* eW = xW + (size_t)N * TS16;

    int nbN = (N + UPB - 1) / UPB;
    int nbE = (E + UPB - 1) / UPB;
    precompute_kernel<<<nbN + nbE, 256, 0, stream>>>(x, e, W, b, xW, eW, N, E, nbN);

    int sBlocks = (nnz + 255) / 256;
    if (haveWs) {
        fused_kernel<<<sBlocks, 256, 0, stream>>>(rows, cols, xW, eW,
                                                  out_idx0, out_idx1, out_attr, nnz);
    } else {
        sheaf_kernel<<<sBlocks, 256, 0, stream>>>(rows, cols, xW, eW, out_attr, nnz);
        int tot = nnz * 36;
        int iBlocks = (tot / 4 + 255) / 256;
        idx_kernel<<<iBlocks, 256, 0, stream>>>(rows, cols, out_idx0, out_idx1, tot);
    }
}

// Round 8
// 123.067 us; speedup vs baseline: 1.1389x; 1.1389x over previous
//
#include <hip/hip_runtime.h>
#include <hip/hip_bf16.h>

#define DD 6
#define FF 64
#define NS 30     // 2*D*RANK + D
#define TS16 32   // bf16 elements per table row (64 B)
#define UPB 32    // units per block in precompute

typedef float fx4 __attribute__((ext_vector_type(4)));

__device__ __forceinline__ float fast_sigmoid(float v) {
    return __builtin_amdgcn_rcpf(1.0f + __expf(-v));
}
__device__ __forceinline__ void nt_store4(float* p, float a, float b, float c, float d) {
    fx4 v = {a, b, c, d};
    __builtin_nontemporal_store(v, (fx4*)p);
}

// ---- device bodies (R5-proven mechanics) ----

__device__ __forceinline__ void precompute_body(
    const float* __restrict__ x, const float* __restrict__ e,
    const float* __restrict__ W, const float* __restrict__ bias,
    __hip_bfloat16* __restrict__ xW, __hip_bfloat16* __restrict__ eW,
    int N, int E, int nbN, int blk)
{
    __shared__ float means[UPB][68];
    bool isNode = blk < nbN;
    int ucount  = isNode ? N : E;
    int ubase   = (isNode ? blk : (blk - nbN)) * UPB;
    const float* src = isNode ? x : e;
    const float* Wp  = W + (isNode ? 0 : FF * NS);
    __hip_bfloat16* dst = isNode ? xW : eW;

    int tid = threadIdx.x, wid = tid >> 6, lane = tid & 63;

    #pragma unroll
    for (int i = 0; i < 8; ++i) {
        int s = wid * 8 + i;
        int u = ubase + s;
        float m = 0.f;
        if (u < ucount) {
            const float* p = src + (size_t)u * (DD * FF) + lane;
            #pragma unroll
            for (int d = 0; d < DD; ++d) m += p[d * FF];
        }
        means[s][lane] = m * (1.0f / 6.0f);
    }
    __syncthreads();

    int j30 = lane & 31;
    bool jval = j30 < NS;
    int j = jval ? j30 : 0;
    float wreg[FF];
    #pragma unroll
    for (int f = 0; f < FF; ++f) wreg[f] = Wp[f * NS + j];   // 15 KB, L1-resident
    float bj = isNode ? bias[j] : 0.f;

    #pragma unroll
    for (int t = 0; t < 4; ++t) {
        int sl = wid * 8 + 2 * t + (lane >> 5);
        int u  = ubase + sl;
        const fx4* mp4 = (const fx4*)(&means[sl][0]);
        float o = bj;
        #pragma unroll
        for (int q = 0; q < 16; ++q) {
            fx4 m4 = mp4[q];
            o = fmaf(m4.x, wreg[4 * q + 0], o);
            o = fmaf(m4.y, wreg[4 * q + 1], o);
            o = fmaf(m4.z, wreg[4 * q + 2], o);
            o = fmaf(m4.w, wreg[4 * q + 3], o);
        }
        if (jval && u < ucount)
            dst[(size_t)u * TS16 + j30] = __float2bfloat16(o);
    }
}

__device__ __forceinline__ void idx_body(
    const int* __restrict__ rows, const int* __restrict__ cols,
    float* __restrict__ out_idx0, float* __restrict__ out_idx1,
    int tot, int ib)
{
    int g = (ib * 256 + (int)threadIdx.x) * 4;
    if (g >= tot) return;
    float v0[4], v1[4];
    #pragma unroll
    for (int i = 0; i < 4; ++i) {
        int gg = g + i;
        int l  = gg / 36;
        int m  = gg - l * 36;
        int m6 = m / 6;
        v0[i] = (float)(6 * rows[l] + m6);
        v1[i] = (float)(6 * cols[l] + (m - m6 * 6));
    }
    nt_store4(out_idx0 + g, v0[0], v0[1], v0[2], v0[3]);
    nt_store4(out_idx1 + g, v1[0], v1[1], v1[2], v1[3]);
}

// ---- Kernel A: heterogeneous grid. Blocks [0,nbPre) run precompute (read-heavy),
// blocks [nbPre, nbPre+iBlocks) stream the idx outputs (write-heavy, independent
// of the tables). Overlapping them fills both BW directions in one dispatch. ----
__global__ __launch_bounds__(256) void pre_idx_kernel(
    const float* __restrict__ x, const float* __restrict__ e,
    const float* __restrict__ W, const float* __restrict__ bias,
    __hip_bfloat16* __restrict__ xW, __hip_bfloat16* __restrict__ eW,
    const int* __restrict__ rows, const int* __restrict__ cols,
    float* __restrict__ out_idx0, float* __restrict__ out_idx1,
    int N, int E, int nbN, int nbPre, int nnz)
{
    if ((int)blockIdx.x < nbPre) {
        precompute_body(x, e, W, bias, xW, eW, N, E, nbN, (int)blockIdx.x);
    } else {
        idx_body(rows, cols, out_idx0, out_idx1, nnz * 36, (int)blockIdx.x - nbPre);
    }
}

// ---- Kernel B: sheaf attrs only (R5-proven: stride-37 LDS, block barriers,
// scalar staging writes; conflict-free lane*37%32 pattern; nt store-out). ----
__global__ __launch_bounds__(256) void sheaf_kernel(
    const int* __restrict__ rows, const int* __restrict__ cols,
    const __hip_bfloat16* __restrict__ xW, const __hip_bfloat16* __restrict__ eW,
    float* __restrict__ out_attr, int nnz)
{
    __shared__ float mlds[4][32 * 37];
    int tid = threadIdx.x, wid = tid >> 6, lane = tid & 63;
    int bb  = blockIdx.x * 256;
    int k   = bb + tid;
    bool act = k < nnz;
    float mp[36];
    if (act) {
        int r = rows[k];
        int c = cols[k];
        const uint4* xp = (const uint4*)(xW + (size_t)r * TS16);
        const uint4* ep = (const uint4*)(eW + (size_t)c * TS16);
        uint4 xa0 = xp[0], xa1 = xp[1], xa2 = xp[2], xa3 = xp[3];
        uint4 ea0 = ep[0], ea1 = ep[1], ea2 = ep[2], ea3 = ep[3];
        uint wx[16] = {xa0.x, xa0.y, xa0.z, xa0.w, xa1.x, xa1.y, xa1.z, xa1.w,
                       xa2.x, xa2.y, xa2.z, xa2.w, xa3.x, xa3.y, xa3.z, xa3.w};
        uint we[16] = {ea0.x, ea0.y, ea0.z, ea0.w, ea1.x, ea1.y, ea1.z, ea1.w,
                       ea2.x, ea2.y, ea2.z, ea2.w, ea3.x, ea3.y, ea3.z, ea3.w};
        float s[NS];
        #pragma unroll
        for (int j2 = 0; j2 < NS; ++j2) {
            uint ux = (j2 & 1) ? (wx[j2 >> 1] & 0xffff0000u) : (wx[j2 >> 1] << 16);
            uint ue = (j2 & 1) ? (we[j2 >> 1] & 0xffff0000u) : (we[j2 >> 1] << 16);
            s[j2] = fast_sigmoid(__uint_as_float(ux) + __uint_as_float(ue));
        }
        #pragma unroll
        for (int i = 0; i < DD; ++i) {
            float a0 = s[i * 2], a1 = s[i * 2 + 1];
            #pragma unroll
            for (int jj = 0; jj < DD; ++jj) {
                float v = fmaf(a0, s[12 + jj * 2], a1 * s[13 + jj * 2]);
                if (i == jj) v += s[24 + i];
                mp[i * 6 + jj] = v;
            }
        }
    }
    float* wl = mlds[wid];
    int wbase = bb + wid * 64;
    #pragma unroll
    for (int h = 0; h < 2; ++h) {
        if (h) __syncthreads();
        if (act && (lane >> 5) == h) {
            float* ml = wl + (lane & 31) * 37;
            #pragma unroll
            for (int m = 0; m < 36; ++m) ml[m] = mp[m];
        }
        __syncthreads();
        int b2  = wbase + h * 32;
        int cnt = nnz - b2; if (cnt > 32) cnt = 32;
        if (cnt > 0) {
            int tot = cnt * 36;
            float* gp = out_attr + (size_t)b2 * 36;
            for (int g = lane * 4; g < tot; g += 256) {
                int l = g / 36;
                int m = g - l * 36;
                const float* mlp = wl + l * 37 + m;
                nt_store4(gp + g, mlp[0], mlp[1], mlp[2], mlp[3]);
            }
        }
    }
}

// Standalone idx kernel for the fallback path (tables staged in idx0 region).
__global__ __launch_bounds__(256) void idx_kernel(
    const int* __restrict__ rows, const int* __restrict__ cols,
    float* __restrict__ out_idx0, float* __restrict__ out_idx1, int tot)
{
    idx_body(rows, cols, out_idx0, out_idx1, tot, (int)blockIdx.x);
}

extern "C" void kernel_launch(void* const* d_in, const int* in_sizes, int n_in,
                              void* d_out, int out_size, void* d_ws, size_t ws_size,
                              hipStream_t stream)
{
    const float* x = (const float*)d_in[0];
    const float* e = (const float*)d_in[1];
    const float* W = (const float*)d_in[2];
    const float* b = (const float*)d_in[3];
    const int* hidx = (const int*)d_in[4];

    int N   = in_sizes[0] / (DD * FF);
    int E   = in_sizes[1] / (DD * FF);
    int nnz = in_sizes[4] / 2;
    const int* rows = hidx;
    const int* cols = hidx + nnz;

    float* out = (float*)d_out;
    size_t M = (size_t)nnz * 36;
    float* out_idx0 = out;
    float* out_idx1 = out + M;
    float* out_attr = out + 2 * M;

    size_t tableBytes = ((size_t)N + (size_t)E) * TS16 * sizeof(__hip_bfloat16);
    bool haveWs = (ws_size >= tableBytes);
    __hip_bfloat16* xW = haveWs ? (__hip_bfloat16*)d_ws
                                : (__hip_bfloat16*)out_idx0;   // fallback staging
    __hip_bfloat16* eW = xW + (size_t)N * TS16;

    int nbN = (N + UPB - 1) / UPB;
    int nbE = (E + UPB - 1) / UPB;
    int nbPre = nbN + nbE;
    int tot = nnz * 36;
    int iBlocks = (tot / 4 + 255) / 256;
    int sBlocks = (nnz + 255) / 256;

    if (haveWs) {
        // A: precompute (reads) overlapped with idx streaming (writes).
        pre_idx_kernel<<<nbPre + iBlocks, 256, 0, stream>>>(
            x, e, W, b, xW, eW, rows, cols, out_idx0, out_idx1,
            N, E, nbN, nbPre, nnz);
        // B: gather + attrs.
        sheaf_kernel<<<sBlocks, 256, 0, stream>>>(rows, cols, xW, eW, out_attr, nnz);
    } else {
        // Tables live in the idx0 output region: idx writes must come last.
        pre_idx_kernel<<<nbPre, 256, 0, stream>>>(
            x, e, W, b, xW, eW, rows, cols, out_idx0, out_idx1,
            N, E, nbN, nbPre, nnz);
        sheaf_kernel<<<sBlocks, 256, 0, stream>>>(rows, cols, xW, eW, out_attr, nnz);
        idx_kernel<<<iBlocks, 256, 0, stream>>>(rows, cols, out_idx0, out_idx1, tot);
    }
}

// Round 9
// 122.632 us; speedup vs baseline: 1.1429x; 1.0035x over previous
//
#include <hip/hip_runtime.h>
#include <hip/hip_bf16.h>

#define DD 6
#define FF 64
#define NS 30     // 2*D*RANK + D
#define TS16 32   // bf16 elements per table row (64 B)
#define UPB 32    // units per block in precompute

typedef float fx4 __attribute__((ext_vector_type(4)));

__device__ __forceinline__ float fast_sigmoid(float v) {
    return __builtin_amdgcn_rcpf(1.0f + __expf(-v));
}
__device__ __forceinline__ void nt_store4(float* p, float a, float b, float c, float d) {
    fx4 v = {a, b, c, d};
    __builtin_nontemporal_store(v, (fx4*)p);
}

// ---- device bodies ----

__device__ __forceinline__ void precompute_body(
    const float* __restrict__ x, const float* __restrict__ e,
    const float* __restrict__ W, const float* __restrict__ bias,
    __hip_bfloat16* __restrict__ xW, __hip_bfloat16* __restrict__ eW,
    int N, int E, int nbN, int blk)
{
    __shared__ float means[UPB][68];
    bool isNode = blk < nbN;
    int ucount  = isNode ? N : E;
    int ubase   = (isNode ? blk : (blk - nbN)) * UPB;
    const float* src = isNode ? x : e;
    const float* Wp  = W + (isNode ? 0 : FF * NS);
    __hip_bfloat16* dst = isNode ? xW : eW;

    int tid = threadIdx.x, wid = tid >> 6, lane = tid & 63;

    #pragma unroll
    for (int i = 0; i < 8; ++i) {
        int s = wid * 8 + i;
        int u = ubase + s;
        float m = 0.f;
        if (u < ucount) {
            const float* p = src + (size_t)u * (DD * FF) + lane;
            #pragma unroll
            for (int d = 0; d < DD; ++d) m += p[d * FF];
        }
        means[s][lane] = m * (1.0f / 6.0f);
    }
    __syncthreads();

    int j30 = lane & 31;
    bool jval = j30 < NS;
    int j = jval ? j30 : 0;
    float wreg[FF];
    #pragma unroll
    for (int f = 0; f < FF; ++f) wreg[f] = Wp[f * NS + j];   // 15 KB, L1-resident
    float bj = isNode ? bias[j] : 0.f;

    #pragma unroll
    for (int t = 0; t < 4; ++t) {
        int sl = wid * 8 + 2 * t + (lane >> 5);
        int u  = ubase + sl;
        const fx4* mp4 = (const fx4*)(&means[sl][0]);
        float o = bj;
        #pragma unroll
        for (int q = 0; q < 16; ++q) {
            fx4 m4 = mp4[q];
            o = fmaf(m4.x, wreg[4 * q + 0], o);
            o = fmaf(m4.y, wreg[4 * q + 1], o);
            o = fmaf(m4.z, wreg[4 * q + 2], o);
            o = fmaf(m4.w, wreg[4 * q + 3], o);
        }
        if (jval && u < ucount)
            dst[(size_t)u * TS16 + j30] = __float2bfloat16(o);
    }
}

__device__ __forceinline__ void idx_body(
    const int* __restrict__ rows, const int* __restrict__ cols,
    float* __restrict__ out_idx0, float* __restrict__ out_idx1,
    int tot, int ib)
{
    int g = (ib * 256 + (int)threadIdx.x) * 4;
    if (g >= tot) return;
    float v0[4], v1[4];
    #pragma unroll
    for (int i = 0; i < 4; ++i) {
        int gg = g + i;
        int l  = gg / 36;
        int m  = gg - l * 36;
        int m6 = m / 6;
        v0[i] = (float)(6 * rows[l] + m6);
        v1[i] = (float)(6 * cols[l] + (m - m6 * 6));
    }
    nt_store4(out_idx0 + g, v0[0], v0[1], v0[2], v0[3]);
    nt_store4(out_idx1 + g, v1[0], v1[1], v1[2], v1[3]);
}

// Sheaf body, wave-autonomous: no __syncthreads. Per-wave 32x37 LDS slice
// (stride-37 scalar staging: lane*37%32 conflict-free — R5/R8-proven); r/c
// staged to each thread's OWN rlds/clds slot, read only within the wave
// (R7-proven); compiler fences delimit LDS phases, HW per-wave in-order DS
// pipe provides write->read ordering.
__device__ __forceinline__ void sheaf_body(
    const int* __restrict__ rows, const int* __restrict__ cols,
    const __hip_bfloat16* __restrict__ xW, const __hip_bfloat16* __restrict__ eW,
    float* __restrict__ out_attr, int nnz, int blk)
{
    __shared__ float mlds[4][32 * 37];
    __shared__ int rlds[256], clds[256];
    int tid = threadIdx.x, wid = tid >> 6, lane = tid & 63;
    int bb  = blk * 256;
    int k   = bb + tid;
    bool act = k < nnz;
    float mp[36];
    if (act) {
        int r = rows[k];
        int c = cols[k];
        rlds[tid] = r;                       // own slot; wave-local reads only
        clds[tid] = c;
        const uint4* xp = (const uint4*)(xW + (size_t)r * TS16);
        const uint4* ep = (const uint4*)(eW + (size_t)c * TS16);
        uint4 xa0 = xp[0], xa1 = xp[1], xa2 = xp[2], xa3 = xp[3];
        uint4 ea0 = ep[0], ea1 = ep[1], ea2 = ep[2], ea3 = ep[3];
        uint wx[16] = {xa0.x, xa0.y, xa0.z, xa0.w, xa1.x, xa1.y, xa1.z, xa1.w,
                       xa2.x, xa2.y, xa2.z, xa2.w, xa3.x, xa3.y, xa3.z, xa3.w};
        uint we[16] = {ea0.x, ea0.y, ea0.z, ea0.w, ea1.x, ea1.y, ea1.z, ea1.w,
                       ea2.x, ea2.y, ea2.z, ea2.w, ea3.x, ea3.y, ea3.z, ea3.w};
        float s[NS];
        #pragma unroll
        for (int j2 = 0; j2 < NS; ++j2) {
            uint ux = (j2 & 1) ? (wx[j2 >> 1] & 0xffff0000u) : (wx[j2 >> 1] << 16);
            uint ue = (j2 & 1) ? (we[j2 >> 1] & 0xffff0000u) : (we[j2 >> 1] << 16);
            s[j2] = fast_sigmoid(__uint_as_float(ux) + __uint_as_float(ue));
        }
        #pragma unroll
        for (int i = 0; i < DD; ++i) {
            float a0 = s[i * 2], a1 = s[i * 2 + 1];
            #pragma unroll
            for (int jj = 0; jj < DD; ++jj) {
                float v = fmaf(a0, s[12 + jj * 2], a1 * s[13 + jj * 2]);
                if (i == jj) v += s[24 + i];
                mp[i * 6 + jj] = v;
            }
        }
    }
    float* wl = mlds[wid];
    int wbase = bb + wid * 64;
    #pragma unroll
    for (int h = 0; h < 2; ++h) {
        if (act && (lane >> 5) == h) {
            float* ml = wl + (lane & 31) * 37;
            #pragma unroll
            for (int m = 0; m < 36; ++m) ml[m] = mp[m];
        }
        asm volatile("" ::: "memory");       // staging before reads (compiler order)
        int b2  = wbase + h * 32;
        int cnt = nnz - b2; if (cnt > 32) cnt = 32;
        if (cnt > 0) {
            int tot = cnt * 36;
            float* gp = out_attr + (size_t)b2 * 36;
            int lb = wid * 64 + h * 32;      // this wave's own slots
            for (int g = lane * 4; g < tot; g += 256) {
                int l = g / 36;
                int m = g - l * 36;
                const float* mlp = wl + l * 37 + m;
                nt_store4(gp + g, mlp[0], mlp[1], mlp[2], mlp[3]);
                (void)lb;
            }
        }
        asm volatile("" ::: "memory");       // reads done before next half overwrites
    }
}

// ---- Kernel A: precompute blocks + first chunk of idx streaming ----
__global__ __launch_bounds__(256) void pre_idx_kernel(
    const float* __restrict__ x, const float* __restrict__ e,
    const float* __restrict__ W, const float* __restrict__ bias,
    __hip_bfloat16* __restrict__ xW, __hip_bfloat16* __restrict__ eW,
    const int* __restrict__ rows, const int* __restrict__ cols,
    float* __restrict__ out_idx0, float* __restrict__ out_idx1,
    int N, int E, int nbN, int nbPre, int nnz)
{
    if ((int)blockIdx.x < nbPre) {
        precompute_body(x, e, W, bias, xW, eW, N, E, nbN, (int)blockIdx.x);
    } else {
        idx_body(rows, cols, out_idx0, out_idx1, nnz * 36, (int)blockIdx.x - nbPre);
    }
}

// ---- Kernel B: sheaf blocks + second chunk of idx streaming (write work to
// fill BW while sheaf waves stall on random table gathers) ----
__global__ __launch_bounds__(256) void sheaf_idx_kernel(
    const int* __restrict__ rows, const int* __restrict__ cols,
    const __hip_bfloat16* __restrict__ xW, const __hip_bfloat16* __restrict__ eW,
    float* __restrict__ out_attr,
    float* __restrict__ out_idx0, float* __restrict__ out_idx1,
    int nnz, int sheafBlocks, int idxBase)
{
    if ((int)blockIdx.x < sheafBlocks) {
        sheaf_body(rows, cols, xW, eW, out_attr, nnz, (int)blockIdx.x);
    } else {
        idx_body(rows, cols, out_idx0, out_idx1, nnz * 36,
                 idxBase + (int)blockIdx.x - sheafBlocks);
    }
}

// Standalone idx kernel (fallback path only).
__global__ __launch_bounds__(256) void idx_kernel(
    const int* __restrict__ rows, const int* __restrict__ cols,
    float* __restrict__ out_idx0, float* __restrict__ out_idx1, int tot)
{
    idx_body(rows, cols, out_idx0, out_idx1, tot, (int)blockIdx.x);
}

extern "C" void kernel_launch(void* const* d_in, const int* in_sizes, int n_in,
                              void* d_out, int out_size, void* d_ws, size_t ws_size,
                              hipStream_t stream)
{
    const float* x = (const float*)d_in[0];
    const float* e = (const float*)d_in[1];
    const float* W = (const float*)d_in[2];
    const float* b = (const float*)d_in[3];
    const int* hidx = (const int*)d_in[4];

    int N   = in_sizes[0] / (DD * FF);
    int E   = in_sizes[1] / (DD * FF);
    int nnz = in_sizes[4] / 2;
    const int* rows = hidx;
    const int* cols = hidx + nnz;

    float* out = (float*)d_out;
    size_t M = (size_t)nnz * 36;
    float* out_idx0 = out;
    float* out_idx1 = out + M;
    float* out_attr = out + 2 * M;

    size_t tableBytes = ((size_t)N + (size_t)E) * TS16 * sizeof(__hip_bfloat16);
    bool haveWs = (ws_size >= tableBytes);
    __hip_bfloat16* xW = haveWs ? (__hip_bfloat16*)d_ws
                                : (__hip_bfloat16*)out_idx0;   // fallback staging
    __hip_bfloat16* eW = xW + (size_t)N * TS16;

    int nbN = (N + UPB - 1) / UPB;
    int nbE = (E + UPB - 1) / UPB;
    int nbPre = nbN + nbE;
    int tot = nnz * 36;
    int iBlocks = (tot / 4 + 255) / 256;
    int sBlocks = (nnz + 255) / 256;

    if (haveWs) {
        int iA = (iBlocks + 1) / 2;          // half the idx stream with precompute
        int iB = iBlocks - iA;               // other half overlaps the gathers
        pre_idx_kernel<<<nbPre + iA, 256, 0, stream>>>(
            x, e, W, b, xW, eW, rows, cols, out_idx0, out_idx1,
            N, E, nbN, nbPre, nnz);
        sheaf_idx_kernel<<<sBlocks + iB, 256, 0, stream>>>(
            rows, cols, xW, eW, out_attr, out_idx0, out_idx1,
            nnz, sBlocks, iA);
    } else {
        // Tables live in the idx0 output region: idx writes must come last.
        pre_idx_kernel<<<nbPre, 256, 0, stream>>>(
            x, e, W, b, xW, eW, rows, cols, out_idx0, out_idx1,
            N, E, nbN, nbPre, nnz);
        sheaf_idx_kernel<<<sBlocks, 256, 0, stream>>>(
            rows, cols, xW, eW, out_attr, out_idx0, out_idx1,
            nnz, sBlocks, 0);
        idx_kernel<<<iBlocks, 256, 0, stream>>>(rows, cols, out_idx0, out_idx1, tot);
    }
}